// Round 9
// baseline (336.771 us; speedup 1.0000x reference)
//
#include <hip/hip_runtime.h>

#define T_TOK 2048
#define S_LEN 1024
#define HIDN  2880
#define NHQ   64
#define NHKV  8
#define DH    64
#define QSZ   4096
#define KVSZ  512
#define WIN   128
#define NQKV  5120
#define NOPAD 2944
#define NT    45        // 2880 / 64 K-tiles (qkv)
#define NTO   64        // 4096 / 64 K-tiles (o-proj)

typedef __attribute__((ext_vector_type(4))) float f32x4;
typedef __attribute__((ext_vector_type(8))) short bf16x8;
typedef __attribute__((ext_vector_type(4))) short s16x4;

__device__ __forceinline__ unsigned short f2bf(float f) {
  unsigned u = __float_as_uint(f);
  u += 0x7fffu + ((u >> 16) & 1u);
  return (unsigned short)(u >> 16);
}
__device__ __forceinline__ float bf2f(unsigned short s) {
  return __uint_as_float(((unsigned)s) << 16);
}
__device__ __forceinline__ void ld_g2l16(const void* g, void* l) {
  __builtin_amdgcn_global_load_lds(
      (const __attribute__((address_space(1))) unsigned int*)g,
      (__attribute__((address_space(3))) unsigned int*)l, 16, 0, 0);
}

// ---------- merged prep: hidden fp32->bf16 + Wq/Wk/Wv transpose ----------
#define NB_CONV 2880
#define NB_WQ   5760
#define NB_WK   720

__device__ __forceinline__ void transpose_tile(
    const float* __restrict__ W, unsigned short* __restrict__ WT,
    int N, int lbid, float (*tile)[72])
{
  const int tid = threadIdx.x;
  const int nbx = N >> 6;
  const int nb = (lbid % nbx) * 64;
  const int kb = (lbid / nbx) * 32;
  const int kk = tid >> 3;
  const int n8 = (tid & 7) * 8;
  const float* src = W + (size_t)(kb + kk) * N + nb + n8;
  *(f32x4*)&tile[kk][n8]     = *(const f32x4*)(src);
  *(f32x4*)&tile[kk][n8 + 4] = *(const f32x4*)(src + 4);
  __syncthreads();
  const int n  = tid & 63;
  const int k8 = (tid >> 6) * 8;
  bf16x8 p;
  #pragma unroll
  for (int j = 0; j < 8; ++j) p[j] = (short)f2bf(tile[k8 + j][n]);
  *(bf16x8*)(WT + (size_t)(nb + n) * HIDN + kb + k8) = p;
}

__global__ __launch_bounds__(256) void prep_kernel(
    const float* __restrict__ hidden, unsigned short* __restrict__ hbf,
    const float* __restrict__ Wq, const float* __restrict__ Wk,
    const float* __restrict__ Wv, unsigned short* __restrict__ WT)
{
  __shared__ float tile[32][72];
  const int bid = blockIdx.x;
  if (bid < NB_CONV) {
    const size_t off = ((size_t)bid * 256 + threadIdx.x) * 8;
    const f32x4 a = *(const f32x4*)(hidden + off);
    const f32x4 b = *(const f32x4*)(hidden + off + 4);
    bf16x8 p;
    p[0] = (short)f2bf(a[0]); p[1] = (short)f2bf(a[1]);
    p[2] = (short)f2bf(a[2]); p[3] = (short)f2bf(a[3]);
    p[4] = (short)f2bf(b[0]); p[5] = (short)f2bf(b[1]);
    p[6] = (short)f2bf(b[2]); p[7] = (short)f2bf(b[3]);
    *(bf16x8*)(hbf + off) = p;
  } else if (bid < NB_CONV + NB_WQ) {
    transpose_tile(Wq, WT, QSZ, bid - NB_CONV, tile);
  } else if (bid < NB_CONV + NB_WQ + NB_WK) {
    transpose_tile(Wk, WT + (size_t)QSZ * HIDN, KVSZ,
                   bid - NB_CONV - NB_WQ, tile);
  } else {
    transpose_tile(Wv, WT + (size_t)(QSZ + KVSZ) * HIDN, KVSZ,
                   bid - NB_CONV - NB_WQ - NB_WK, tile);
  }
}

// ---- Wo [K=4096][N=2880] fp32 -> WT [2944 pad][4096] bf16 (fallback path) -
__global__ __launch_bounds__(256) void transpose_w(
    const float* __restrict__ W, unsigned short* __restrict__ WT,
    int K, int N)
{
  __shared__ float tile[32][72];
  const int tid = threadIdx.x;
  const int nb = blockIdx.x * 64;
  const int kb = blockIdx.y * 32;
  const int kk = tid >> 3;
  const int n8 = (tid & 7) * 8;
  if (nb + 64 <= N) {
    const float* src = W + (size_t)(kb + kk) * N + nb + n8;
    *(f32x4*)&tile[kk][n8]     = *(const f32x4*)(src);
    *(f32x4*)&tile[kk][n8 + 4] = *(const f32x4*)(src + 4);
  } else {
    #pragma unroll
    for (int u = 0; u < 8; ++u)
      tile[kk][n8 + u] = (nb + n8 + u < N)
          ? W[(size_t)(kb + kk) * N + nb + n8 + u] : 0.f;
  }
  __syncthreads();
  const int n  = tid & 63;
  const int k8 = (tid >> 6) * 8;
  bf16x8 p;
  #pragma unroll
  for (int j = 0; j < 8; ++j) p[j] = (short)f2bf(tile[k8 + j][n]);
  *(bf16x8*)(WT + (size_t)(nb + n) * K + kb + k8) = p;
}

// rope+bias epilogue for a 64-col group, 8 row-frags (per-wave 128 rows).
__device__ __forceinline__ void rope_epilogue8(
    f32x4 (*acc)[4], const float* __restrict__ bias,
    const int* __restrict__ pos, unsigned short* __restrict__ outp,
    int outStride, int colbase, int rowbase, int lane)
{
  const int fr = lane & 15;
  const int r4 = (lane >> 4) * 4;
  const float invf0 = exp2f((float)fr        * (-17.19460283f / 32.0f));
  const float invf1 = exp2f((float)(fr + 16) * (-17.19460283f / 32.0f));
  #pragma unroll
  for (int mt = 0; mt < 8; ++mt) {
    #pragma unroll
    for (int i = 0; i < 4; ++i) {
      const int m = rowbase + mt * 16 + r4 + i;
      const float p = (float)pos[m];
      #pragma unroll
      for (int ntp = 0; ntp < 2; ++ntp) {
        float sv, cv;
        __sincosf(p * (ntp ? invf1 : invf0), &sv, &cv);
        const int c1 = colbase + ntp * 16 + fr;
        const float x1 = acc[mt][ntp][i]     + bias[c1];
        const float x2 = acc[mt][ntp + 2][i] + bias[c1 + 32];
        outp[(size_t)m * outStride + c1]      = f2bf(x1 * cv - x2 * sv);
        outp[(size_t)m * outStride + c1 + 32] = f2bf(x1 * sv + x2 * cv);
      }
    }
  }
}

// ---- fused QKV GEMM: 256x256 tile, 8 waves, v4 single-region schedule.
// Per K-tile: {read all 24 frags (bfr first) -> 4x16 MFMA clusters (LDS reads
// stream under MFMA, no barrier between) -> lgkm(0)+barrier -> stage tile t+2
// into the just-consumed buffer ((t+2)&1 == t&1) -> vmcnt(8) (drains t+1,
// issued a full tile ago) -> barrier}. 2 barriers/K-tile instead of 8; the
// ds-read pipe (2304 cyc) overlaps the MFMA pipe (2480 cyc) instead of
// serializing with it.
// blocks [0,160): GEMM.  blocks [160,256): Wo-transpose riders.
__global__ __launch_bounds__(512, 2) void gemm_qkv(
    const unsigned short* __restrict__ A, const unsigned short* __restrict__ BT,
    const float* __restrict__ bq, const float* __restrict__ bk,
    const float* __restrict__ bv, const int* __restrict__ pos,
    unsigned short* __restrict__ qb, unsigned short* __restrict__ kb,
    unsigned short* __restrict__ vT,
    const float* __restrict__ Wo, unsigned short* __restrict__ WoT)
{
  __shared__ unsigned short lds[65536];   // 128 KiB (2 x 64 KiB buffers)
  const int tid  = threadIdx.x;
  const int bid  = blockIdx.x;

  if (bid >= 160) {
    // ---- Wo transpose rider: 96 blocks x 2 halves x 31 tiles (64n x 32k) --
    const int half = tid >> 8;            // 0..1
    const int ltid = tid & 255;
    float* fb = (float*)lds;
    float (*tile)[72] = (float (*)[72])(fb + half * (32 * 72));
    const int slot = (bid - 160) * 2 + half;     // 0..191
    const int kk = ltid >> 3;
    const int n8 = (ltid & 7) * 8;
    const int n  = ltid & 63;
    const int k8 = (ltid >> 6) * 8;
    f32x4 va = {0.f, 0.f, 0.f, 0.f}, vb = {0.f, 0.f, 0.f, 0.f};
    int nb = 0, kb2 = 0;
    {
      const int t2 = slot * 31;
      if (t2 < 5888) {
        nb = (t2 % 46) * 64; kb2 = (t2 / 46) * 32;
        const float* src = Wo + (size_t)(kb2 + kk) * HIDN + nb + n8;
        if (nb + 64 <= HIDN) {
          va = *(const f32x4*)src; vb = *(const f32x4*)(src + 4);
        } else {
          #pragma unroll
          for (int u = 0; u < 4; ++u) {
            va[u] = (nb + n8 + u     < HIDN) ? src[u]     : 0.f;
            vb[u] = (nb + n8 + 4 + u < HIDN) ? src[4 + u] : 0.f;
          }
        }
      }
    }
    for (int it = 0; it < 31; ++it) {
      const int t2 = slot * 31 + it;
      const bool ok = t2 < 5888;
      const int cnb = nb, ckb = kb2;
      __syncthreads();                    // prior iter's transposed reads done
      if (ok) {
        *(f32x4*)&tile[kk][n8]     = va;
        *(f32x4*)&tile[kk][n8 + 4] = vb;
      }
      __syncthreads();
      const int t2n = t2 + 1;
      if (it + 1 < 31 && t2n < 5888) {    // prefetch next tile into regs
        nb = (t2n % 46) * 64; kb2 = (t2n / 46) * 32;
        const float* src = Wo + (size_t)(kb2 + kk) * HIDN + nb + n8;
        if (nb + 64 <= HIDN) {
          va = *(const f32x4*)src; vb = *(const f32x4*)(src + 4);
        } else {
          #pragma unroll
          for (int u = 0; u < 4; ++u) {
            va[u] = (nb + n8 + u     < HIDN) ? src[u]     : 0.f;
            vb[u] = (nb + n8 + 4 + u < HIDN) ? src[4 + u] : 0.f;
          }
        }
      }
      if (ok) {
        bf16x8 p;
        #pragma unroll
        for (int j = 0; j < 8; ++j) p[j] = (short)f2bf(tile[k8 + j][n]);
        *(bf16x8*)(WoT + (size_t)(cnb + n) * QSZ + ckb + k8) = p;
      }
    }
    return;
  }

  const int lane = tid & 63;
  const int wid  = tid >> 6;              // 0..7
  const int wm   = wid >> 2;              // 0..1  row half
  const int wn   = wid & 3;               // 0..3  64-col group
  const int wg   = (bid & 7) * 20 + (bid >> 3);
  const int n0   = (wg >> 3) * 256;       // n-chunked: B-panel L2-resident/XCD
  const int m0   = (wg & 7) * 256;
  const int fr = lane & 15;
  const int fq = lane >> 4;

  const int rsub = tid >> 3;                    // 0..63
  const int cg   = (tid & 7) ^ (rsub & 7);
  const unsigned short* Asrc = A  + (size_t)(m0 + rsub) * HIDN + cg * 8;
  const unsigned short* Bsrc = BT + (size_t)(n0 + rsub) * HIDN + cg * 8;
  const size_t half_step = (size_t)128 * HIDN;
  const size_t r64 = (size_t)64 * HIDN;

  #define STAGE(src, slot)                                         \
    do {                                                           \
      ld_g2l16((src),       (slot) + (size_t)tid * 8);             \
      ld_g2l16((src) + r64, (slot) + (size_t)(512 + tid) * 8);     \
    } while (0)

  // prologue: tiles 0 (buf0) and 1 (buf1); 16 loads, wait leaves t1's 8
  STAGE(Asrc,                  lds + 0);
  STAGE(Asrc + half_step,      lds + 8192);
  STAGE(Bsrc,                  lds + 16384);
  STAGE(Bsrc + half_step,      lds + 24576);
  STAGE(Asrc + 64,             lds + 32768 + 0);
  STAGE(Asrc + half_step + 64, lds + 32768 + 8192);
  STAGE(Bsrc + 64,             lds + 32768 + 16384);
  STAGE(Bsrc + half_step + 64, lds + 32768 + 24576);
  asm volatile("s_waitcnt vmcnt(8)" ::: "memory");
  __builtin_amdgcn_s_barrier();

  f32x4 acc[8][4];
  #pragma unroll
  for (int i = 0; i < 8; ++i)
    #pragma unroll
    for (int j = 0; j < 4; ++j) acc[i][j] = (f32x4){0.f, 0.f, 0.f, 0.f};

  for (int t = 0; t < NT; ++t) {
    unsigned short* Abuf = lds + (t & 1) * 32768;
    unsigned short* Bbuf = Abuf + 16384;
    const int kP = (t + 2) * 64;          // prefetch K-offset (tile t+2)
    const bool pf = (t <= NT - 3);

    // ---- read all fragments for this tile (bfr first: q0's operands) ----
    bf16x8 bfr[4][2];
    bf16x8 af[8][2];
    #pragma unroll
    for (int nf = 0; nf < 4; ++nf)
      #pragma unroll
      for (int ks = 0; ks < 2; ++ks) {
        const int R = wn * 64 + nf * 16 + fr;
        const int kc = ks * 4 + fq;
        bfr[nf][ks] = *(const bf16x8*)(Bbuf + R * 64 + ((kc ^ (R & 7)) << 3));
      }
    #pragma unroll
    for (int j = 0; j < 8; ++j)
      #pragma unroll
      for (int ks = 0; ks < 2; ++ks) {
        const int R = wm * 128 + j * 16 + fr;
        const int kc = ks * 4 + fq;
        af[j][ks] = *(const bf16x8*)(Abuf + R * 64 + ((kc ^ (R & 7)) << 3));
      }

    // ---- 4 MFMA clusters, no barriers between (reads stream underneath) --
    #pragma unroll
    for (int q = 0; q < 4; ++q) {
      __builtin_amdgcn_s_setprio(1);
      #pragma unroll
      for (int j = 0; j < 2; ++j)
        #pragma unroll
        for (int nf = 0; nf < 4; ++nf)
          #pragma unroll
          for (int ks = 0; ks < 2; ++ks)
            acc[q * 2 + j][nf] = __builtin_amdgcn_mfma_f32_16x16x32_bf16(
                af[q * 2 + j][ks], bfr[nf][ks], acc[q * 2 + j][nf], 0, 0, 0);
      __builtin_amdgcn_s_setprio(0);
    }

    // ---- tile-end sync + stage t+2 into the just-consumed buffer --------
    if (t < NT - 1) {
      asm volatile("s_waitcnt lgkmcnt(0)" ::: "memory");
      __builtin_amdgcn_s_barrier();       // all waves' reads of buf(t) done
      if (pf) {
        STAGE(Asrc + kP,             Abuf);
        STAGE(Asrc + half_step + kP, Abuf + 8192);
        STAGE(Bsrc + kP,             Bbuf);
        STAGE(Bsrc + half_step + kP, Bbuf + 8192);
      }
      if (pf)                asm volatile("s_waitcnt vmcnt(8)" ::: "memory");
      else                   asm volatile("s_waitcnt vmcnt(0)" ::: "memory");
      __builtin_amdgcn_s_barrier();       // t+1 data visible to all waves
    }
  }
  #undef STAGE

  const int cb = n0 + wn * 64;
  const int rowbase = m0 + wm * 128;
  if (cb < QSZ) {
    rope_epilogue8(acc, bq, pos, qb, QSZ, cb, rowbase, lane);
  } else if (cb < QSZ + KVSZ) {
    rope_epilogue8(acc, bk, pos, kb, KVSZ, cb - QSZ, rowbase, lane);
  } else {
    const int r4 = (lane >> 4) * 4;
    #pragma unroll
    for (int nt = 0; nt < 4; ++nt) {
      const int vrow = cb - (QSZ + KVSZ) + nt * 16 + fr;
      const float bvv = bv[vrow];
      #pragma unroll
      for (int mt = 0; mt < 8; ++mt) {
        const int mb = rowbase + mt * 16 + r4;
        s16x4 p;
        p[0] = (short)f2bf(acc[mt][nt][0] + bvv);
        p[1] = (short)f2bf(acc[mt][nt][1] + bvv);
        p[2] = (short)f2bf(acc[mt][nt][2] + bvv);
        p[3] = (short)f2bf(acc[mt][nt][3] + bvv);
        *(s16x4*)(vT + (size_t)vrow * T_TOK + mb) = p;
      }
    }
  }
}

// ------- O-projection GEMM: 256m x 128n tile, 8 waves (4M x 2N),
// 2-phase-per-K-tile, TRIPLE-buffered A + double-buffered B, counted vmcnt.
// XCD swizzle: n-chunked (B=WoT chunk ~3 MB L2-resident per XCD; A streams).
__global__ __launch_bounds__(512, 2) void gemm_o(
    const unsigned short* __restrict__ A, const unsigned short* __restrict__ BT,
    const float* __restrict__ bias, float* __restrict__ C)
{
  __shared__ unsigned short lds[65536];   // 128 KiB
  const int tid  = threadIdx.x;
  const int lane = tid & 63;
  const int wid  = tid >> 6;
  const int wm   = wid >> 1;              // 0..3 row 64-group
  const int wn   = wid & 1;               // 0..1 col 64-group
  const int bid  = blockIdx.x;
  const int wg   = (bid & 7) * 23 + (bid >> 3);   // 184 = 8*23 bijective
  const int m0   = (wg & 7) * 256;        // n-chunked decode
  const int n0   = (wg >> 3) * 128;
  const int fr = lane & 15;
  const int fq = lane >> 4;

  const int rsub = tid >> 3;                    // 0..63
  const int cg   = (tid & 7) ^ (rsub & 7);
  const unsigned short* Asrc = A  + (size_t)(m0 + rsub) * QSZ + cg * 8;
  const unsigned short* Bsrc = BT + (size_t)(n0 + rsub) * QSZ + cg * 8;
  const size_t r64 = (size_t)64 * QSZ;

  #define STA(t, r)  ld_g2l16(Asrc + (size_t)(t) * 64 + (size_t)(r) * r64,   \
      lds + ((t) % 3) * 16384 + ((size_t)(r) * 512 + tid) * 8)
  #define STB(t, r)  ld_g2l16(Bsrc + (size_t)(t) * 64 + (size_t)(r) * r64,   \
      lds + 49152 + ((t) & 1) * 8192 + ((size_t)(r) * 512 + tid) * 8)

  STA(0, 0); STA(0, 1); STA(0, 2); STA(0, 3);
  STB(0, 0); STB(0, 1);
  STA(1, 0); STA(1, 1); STA(1, 2); STA(1, 3);
  STB(1, 0); STB(1, 1);
  asm volatile("s_waitcnt vmcnt(6)" ::: "memory");
  __builtin_amdgcn_s_barrier();

  f32x4 acc[4][4];
  #pragma unroll
  for (int i = 0; i < 4; ++i)
    #pragma unroll
    for (int j = 0; j < 4; ++j) acc[i][j] = (f32x4){0.f, 0.f, 0.f, 0.f};
  bf16x8 bfr[4][2];

  for (int t = 0; t < NTO; ++t) {
    unsigned short* Abuf = lds + (t % 3) * 16384;
    unsigned short* Bbuf = lds + 49152 + (t & 1) * 8192;
    #pragma unroll
    for (int nf = 0; nf < 4; ++nf)
      #pragma unroll
      for (int ks = 0; ks < 2; ++ks) {
        const int R = wn * 64 + nf * 16 + fr;
        const int kc = ks * 4 + fq;
        bfr[nf][ks] = *(const bf16x8*)(Bbuf + R * 64 + ((kc ^ (R & 7)) << 3));
      }
    bf16x8 af0[2][2];
    #pragma unroll
    for (int j = 0; j < 2; ++j)
      #pragma unroll
      for (int ks = 0; ks < 2; ++ks) {
        const int R = wm * 64 + j * 16 + fr;
        const int kc = ks * 4 + fq;
        af0[j][ks] = *(const bf16x8*)(Abuf + R * 64 + ((kc ^ (R & 7)) << 3));
      }
    if (t <= NTO - 3) { STA(t + 2, 0); STA(t + 2, 1); STA(t + 2, 2); STA(t + 2, 3); }
    __builtin_amdgcn_s_barrier();
    __builtin_amdgcn_s_setprio(1);
    #pragma unroll
    for (int j = 0; j < 2; ++j)
      #pragma unroll
      for (int nf = 0; nf < 4; ++nf)
        #pragma unroll
        for (int ks = 0; ks < 2; ++ks)
          acc[j][nf] = __builtin_amdgcn_mfma_f32_16x16x32_bf16(
              af0[j][ks], bfr[nf][ks], acc[j][nf], 0, 0, 0);
    __builtin_amdgcn_s_setprio(0);
    __builtin_amdgcn_s_barrier();
    bf16x8 af1[2][2];
    #pragma unroll
    for (int j = 0; j < 2; ++j)
      #pragma unroll
      for (int ks = 0; ks < 2; ++ks) {
        const int R = wm * 64 + (2 + j) * 16 + fr;
        const int kc = ks * 4 + fq;
        af1[j][ks] = *(const bf16x8*)(Abuf + R * 64 + ((kc ^ (R & 7)) << 3));
      }
    if (t <= NTO - 3) { STB(t + 2, 0); STB(t + 2, 1); }
    if (t <= NTO - 3)      asm volatile("s_waitcnt vmcnt(6)" ::: "memory");
    else if (t == NTO - 2) asm volatile("s_waitcnt vmcnt(0)" ::: "memory");
    __builtin_amdgcn_s_barrier();
    __builtin_amdgcn_s_setprio(1);
    #pragma unroll
    for (int j = 0; j < 2; ++j)
      #pragma unroll
      for (int nf = 0; nf < 4; ++nf)
        #pragma unroll
        for (int ks = 0; ks < 2; ++ks)
          acc[2 + j][nf] = __builtin_amdgcn_mfma_f32_16x16x32_bf16(
              af1[j][ks], bfr[nf][ks], acc[2 + j][nf], 0, 0, 0);
    __builtin_amdgcn_s_setprio(0);
    __builtin_amdgcn_s_barrier();
  }
  #undef STA
  #undef STB

  const int r4 = (lane >> 4) * 4;
  #pragma unroll
  for (int nt = 0; nt < 4; ++nt) {
    const int n = n0 + wn * 64 + nt * 16 + fr;
    if (n >= HIDN) continue;
    const float bvv = bias[n];
    #pragma unroll
    for (int mt = 0; mt < 4; ++mt) {
      const int mb = m0 + wm * 64 + mt * 16 + r4;
      #pragma unroll
      for (int i = 0; i < 4; ++i)
        C[(size_t)(mb + i) * HIDN + n] = acc[mt][nt][i] + bvv;
    }
  }
}

// ---------------- MFMA sliding-window GQA attention, 2 heads/block --------
// Per-wave windowing: wave w owns q-rows [sq0+16w, sq0+16w+15]; its valid key
// range is exactly tiles [w, w+8] (144 keys) of the 192-key staging window.
__global__ __launch_bounds__(256, 3) void attn_kernel(
    const unsigned short* __restrict__ q, const unsigned short* __restrict__ k,
    const unsigned short* __restrict__ vT, unsigned short* __restrict__ o)
{
  __shared__ unsigned short lds[26624];     // 53,248 B -> 3 blocks/CU
  unsigned short* Ks = lds;                 // [192][72]
  unsigned short* Vt = lds;                 // [64][200] (over Ks)
  unsigned short* Ps = lds + 13824;         // [64][200]

  const int tid  = threadIdx.x;
  const int lane = tid & 63;
  const int wid  = tid >> 6;
  const int sq0  = blockIdx.x * 64;
  const int hp   = blockIdx.y;
  const int b    = blockIdx.z;
  const int h0   = hp * 2;
  const int kvh  = hp >> 2;
  const int kp0  = sq0 - WIN;

  const int fr = lane & 15;
  const int fk = (lane >> 4) * 8;
  const int qw = wid * 16;
  const int ntb = wid;                      // wave's first valid K-tile

  bf16x8 qf[2][2];
  {
    const size_t qrow = (size_t)(b * S_LEN + sq0 + qw + fr) * QSZ;
    #pragma unroll
    for (int hh = 0; hh < 2; ++hh)
      #pragma unroll
      for (int ks2 = 0; ks2 < 2; ++ks2)
        qf[hh][ks2] = *(const bf16x8*)(q + qrow + (h0 + hh) * DH + ks2 * 32 + fk);
  }

  #pragma unroll
  for (int j = 0; j < 6; ++j) {
    const int c  = tid + j * 256;
    const int kr = c >> 3, dc = (c & 7) * 8;
    int tok = b * S_LEN + kp0 + kr;
    if (tok < 0) tok = 0;                   // masked later
    const bf16x8 vv = *(const bf16x8*)(k + (size_t)tok * KVSZ + kvh * DH + dc);
    *(bf16x8*)&Ks[kr * 72 + dc] = vv;
  }
  __syncthreads();

  f32x4 S0[9], S1[9];
  #pragma unroll
  for (int i = 0; i < 9; ++i) {
    S0[i] = (f32x4){0.f, 0.f, 0.f, 0.f};
    S1[i] = (f32x4){0.f, 0.f, 0.f, 0.f};
  }
  #pragma unroll
  for (int ks2 = 0; ks2 < 2; ++ks2) {
    #pragma unroll
    for (int j = 0; j < 9; ++j) {
      const bf16x8 bfr =
          *(const bf16x8*)&Ks[((ntb + j) * 16 + fr) * 72 + ks2 * 32 + fk];
      S0[j] = __builtin_amdgcn_mfma_f32_16x16x32_bf16(qf[0][ks2], bfr, S0[j], 0, 0, 0);
      S1[j] = __builtin_amdgcn_mfma_f32_16x16x32_bf16(qf[1][ks2], bfr, S1[j], 0, 0, 0);
    }
  }

  const int qbase = sq0 + qw + ((lane >> 4) << 2);
  float ls0[4] = {0.f, 0.f, 0.f, 0.f};
  float ls1[4] = {0.f, 0.f, 0.f, 0.f};
  #pragma unroll
  for (int j = 0; j < 9; ++j) {
    const int jpos = kp0 + (ntb + j) * 16 + fr;
    #pragma unroll
    for (int i = 0; i < 4; ++i) {
      const int qa = qbase + i;
      const bool valid = (jpos >= 0) && (jpos <= qa) && (jpos >= qa - WIN);
      const float e0 = valid ? __expf(S0[j][i] * 0.125f) : 0.f;
      const float e1 = valid ? __expf(S1[j][i] * 0.125f) : 0.f;
      S0[j][i] = e0; ls0[i] += e0;
      S1[j][i] = e1; ls1[i] += e1;
    }
  }
  #pragma unroll
  for (int off = 1; off < 16; off <<= 1)
    #pragma unroll
    for (int i = 0; i < 4; ++i) {
      ls0[i] += __shfl_xor(ls0[i], off, 64);
      ls1[i] += __shfl_xor(ls1[i], off, 64);
    }
  float inv0[4], inv1[4];
  #pragma unroll
  for (int i = 0; i < 4; ++i) {
    inv0[i] = 1.0f / ls0[i];
    inv1[i] = 1.0f / ls1[i];
  }
  __syncthreads();   // all waves done reading Ks

  #pragma unroll
  for (int j = 0; j < 9; ++j)
    #pragma unroll
    for (int i = 0; i < 4; ++i)
      Ps[(qbase - sq0 + i) * 200 + (ntb + j) * 16 + fr] = f2bf(S0[j][i]);
  {
    const int zt = (wid & 1) ? (wid - 1) : (wid + 9);   // zero-fill tile
    #pragma unroll
    for (int i = 0; i < 4; ++i)
      Ps[(qbase - sq0 + i) * 200 + zt * 16 + fr] = 0;
  }
  if (kp0 >= 0) {
    #pragma unroll
    for (int j = 0; j < 6; ++j) {
      const int c  = tid + j * 256;
      const int dr = c / 24, kc = (c % 24) * 8;
      const bf16x8 vv = *(const bf16x8*)(
          vT + (size_t)(kvh * DH + dr) * T_TOK + b * S_LEN + kp0 + kc);
      *(bf16x8*)&Vt[dr * 200 + kc] = vv;
    }
  } else {
    #pragma unroll
    for (int j = 0; j < 6; ++j) {
      const int c  = tid + j * 256;
      const int dr = c / 24, kc = (c % 24) * 8;
      bf16x8 vv;
      #pragma unroll
      for (int u = 0; u < 8; ++u) {
        int col = b * S_LEN + kp0 + kc + u;
        if (col < 0) col = 0;               // p==0 there
        vv[u] = (short)vT[(size_t)(kvh * DH + dr) * T_TOK + col];
      }
      *(bf16x8*)&Vt[dr * 200 + kc] = vv;
    }
  }
  __syncthreads();

  const int ks0 = wid >> 1;                 // wave's first PV 32-col block
  {
    f32x4 O[4];
    #pragma unroll
    for (int i = 0; i < 4; ++i) O[i] = (f32x4){0.f, 0.f, 0.f, 0.f};
    #pragma unroll
    for (int kq = 0; kq < 5; ++kq) {
      const int ks2 = ks0 + kq;
      const bf16x8 pa = *(const bf16x8*)&Ps[(qw + fr) * 200 + ks2 * 32 + fk];
      #pragma unroll
      for (int nt = 0; nt < 4; ++nt) {
        const bf16x8 vb = *(const bf16x8*)&Vt[(nt * 16 + fr) * 200 + ks2 * 32 + fk];
        O[nt] = __builtin_amdgcn_mfma_f32_16x16x32_bf16(pa, vb, O[nt], 0, 0, 0);
      }
    }
    #pragma unroll
    for (int nt = 0; nt < 4; ++nt)
      #pragma unroll
      for (int i = 0; i < 4; ++i)
        o[(size_t)(b * S_LEN + qbase + i) * QSZ + h0 * DH + nt * 16 + fr] =
            f2bf(O[nt][i] * inv0[i]);
  }
  __syncthreads();   // all waves done reading P0

  #pragma unroll
  for (int j = 0; j < 9; ++j)
    #pragma unroll
    for (int i = 0; i < 4; ++i)
      Ps[(qbase - sq0 + i) * 200 + (ntb + j) * 16 + fr] = f2bf(S1[j][i]);
  __syncthreads();

  {
    f32x4 O[4];
    #pragma unroll
    for (int i = 0; i < 4; ++i) O[i] = (f32x4){0.f, 0.f, 0.f, 0.f};
    #pragma unroll
    for (int kq = 0; kq < 5; ++kq) {
      const int ks2 = ks0 + kq;
      const bf16x8 pa = *(const bf16x8*)&Ps[(qw + fr) * 200 + ks2 * 32 + fk];
      #pragma unroll
      for (int nt = 0; nt < 4; ++nt) {
        const bf16x8 vb = *(const bf16x8*)&Vt[(nt * 16 + fr) * 200 + ks2 * 32 + fk];
        O[nt] = __builtin_amdgcn_mfma_f32_16x16x32_bf16(pa, vb, O[nt], 0, 0, 0);
      }
    }
    #pragma unroll
    for (int nt = 0; nt < 4; ++nt)
      #pragma unroll
      for (int i = 0; i < 4; ++i)
        o[(size_t)(b * S_LEN + qbase + i) * QSZ + (h0 + 1) * DH + nt * 16 + fr] =
            f2bf(O[nt][i] * inv1[i]);
  }
}

extern "C" void kernel_launch(void* const* d_in, const int* in_sizes, int n_in,
                              void* d_out, int out_size, void* d_ws, size_t ws_size,
                              hipStream_t stream) {
  const float* hidden    = (const float*)d_in[0];
  const int*   positions = (const int*)d_in[1];
  const float* Wq = (const float*)d_in[2];
  const float* bq = (const float*)d_in[3];
  const float* Wk = (const float*)d_in[4];
  const float* bk = (const float*)d_in[5];
  const float* Wv = (const float*)d_in[6];
  const float* bv = (const float*)d_in[7];
  const float* Wo = (const float*)d_in[8];
  const float* bo = (const float*)d_in[9];
  float* out = (float*)d_out;

  // workspace:
  //   hbf   [2048][2880] bf16        @ 0          (11,796,480)
  //   WqkvT [5120][2880] bf16        @ 11796480
  //   q/o   [2048][4096] bf16        @ 41287680
  //   k     [2048][512]  bf16        @ 58064896
  //   vT    [512][2048]  bf16        @ 60162048   (ends 62,259,200)
  //   WoT   [2944][4096] bf16        @ 62259200   (needs ws >= 86,376,448)
  char* ws = (char*)d_ws;
  unsigned short* hbf   = (unsigned short*)(ws);
  unsigned short* WqkvT = (unsigned short*)(ws + 11796480);
  unsigned short* qb    = (unsigned short*)(ws + 41287680);
  unsigned short* kb    = (unsigned short*)(ws + 58064896);
  unsigned short* vTb   = (unsigned short*)(ws + 60162048);

  const bool merged = ws_size >= (size_t)86376448;
  unsigned short* WoT = merged ? (unsigned short*)(ws + 62259200) : WqkvT;

  prep_kernel<<<dim3(NB_CONV + NB_WQ + 2 * NB_WK), dim3(256), 0, stream>>>(
      hidden, hbf, Wq, Wk, Wv, WqkvT);

  if (merged) {
    // 96 looping Wo-transpose riders fill the CUs the 160 GEMM blocks leave idle
    gemm_qkv<<<dim3(256), dim3(512), 0, stream>>>(
        hbf, WqkvT, bq, bk, bv, positions, qb, kb, vTb, Wo, WoT);
  } else {
    gemm_qkv<<<dim3(160), dim3(512), 0, stream>>>(
        hbf, WqkvT, bq, bk, bv, positions, qb, kb, vTb, Wo, WoT);
    transpose_w<<<dim3(NOPAD / 64, QSZ / 32), dim3(256), 0, stream>>>(
        Wo, WqkvT, QSZ, HIDN);
  }

  attn_kernel<<<dim3(S_LEN / 64, NHQ / 2, 2), dim3(256), 0, stream>>>(
      qb, kb, vTb, qb);
  gemm_o<<<dim3(184), dim3(512), 0, stream>>>(
      qb, WoT, bo, out);
}

// Round 10
// 327.325 us; speedup vs baseline: 1.0289x; 1.0289x over previous
//
#include <hip/hip_runtime.h>

#define T_TOK 2048
#define S_LEN 1024
#define HIDN  2880
#define NHQ   64
#define NHKV  8
#define DH    64
#define QSZ   4096
#define KVSZ  512
#define WIN   128
#define NQKV  5120
#define NOPAD 2944
#define NT    45        // 2880 / 64 K-tiles (qkv)
#define NTO   64        // 4096 / 64 K-tiles (o-proj)

typedef __attribute__((ext_vector_type(4))) float f32x4;
typedef __attribute__((ext_vector_type(8))) short bf16x8;
typedef __attribute__((ext_vector_type(4))) short s16x4;

__device__ __forceinline__ unsigned short f2bf(float f) {
  unsigned u = __float_as_uint(f);
  u += 0x7fffu + ((u >> 16) & 1u);
  return (unsigned short)(u >> 16);
}
__device__ __forceinline__ float bf2f(unsigned short s) {
  return __uint_as_float(((unsigned)s) << 16);
}
__device__ __forceinline__ void ld_g2l16(const void* g, void* l) {
  __builtin_amdgcn_global_load_lds(
      (const __attribute__((address_space(1))) unsigned int*)g,
      (__attribute__((address_space(3))) unsigned int*)l, 16, 0, 0);
}

// ---------- merged prep: hidden fp32->bf16 + Wq/Wk/Wv transpose ----------
#define NB_CONV 2880
#define NB_WQ   5760
#define NB_WK   720

__device__ __forceinline__ void transpose_tile(
    const float* __restrict__ W, unsigned short* __restrict__ WT,
    int N, int lbid, float (*tile)[72])
{
  const int tid = threadIdx.x;
  const int nbx = N >> 6;
  const int nb = (lbid % nbx) * 64;
  const int kb = (lbid / nbx) * 32;
  const int kk = tid >> 3;
  const int n8 = (tid & 7) * 8;
  const float* src = W + (size_t)(kb + kk) * N + nb + n8;
  *(f32x4*)&tile[kk][n8]     = *(const f32x4*)(src);
  *(f32x4*)&tile[kk][n8 + 4] = *(const f32x4*)(src + 4);
  __syncthreads();
  const int n  = tid & 63;
  const int k8 = (tid >> 6) * 8;
  bf16x8 p;
  #pragma unroll
  for (int j = 0; j < 8; ++j) p[j] = (short)f2bf(tile[k8 + j][n]);
  *(bf16x8*)(WT + (size_t)(nb + n) * HIDN + kb + k8) = p;
}

__global__ __launch_bounds__(256) void prep_kernel(
    const float* __restrict__ hidden, unsigned short* __restrict__ hbf,
    const float* __restrict__ Wq, const float* __restrict__ Wk,
    const float* __restrict__ Wv, unsigned short* __restrict__ WT)
{
  __shared__ float tile[32][72];
  const int bid = blockIdx.x;
  if (bid < NB_CONV) {
    const size_t off = ((size_t)bid * 256 + threadIdx.x) * 8;
    const f32x4 a = *(const f32x4*)(hidden + off);
    const f32x4 b = *(const f32x4*)(hidden + off + 4);
    bf16x8 p;
    p[0] = (short)f2bf(a[0]); p[1] = (short)f2bf(a[1]);
    p[2] = (short)f2bf(a[2]); p[3] = (short)f2bf(a[3]);
    p[4] = (short)f2bf(b[0]); p[5] = (short)f2bf(b[1]);
    p[6] = (short)f2bf(b[2]); p[7] = (short)f2bf(b[3]);
    *(bf16x8*)(hbf + off) = p;
  } else if (bid < NB_CONV + NB_WQ) {
    transpose_tile(Wq, WT, QSZ, bid - NB_CONV, tile);
  } else if (bid < NB_CONV + NB_WQ + NB_WK) {
    transpose_tile(Wk, WT + (size_t)QSZ * HIDN, KVSZ,
                   bid - NB_CONV - NB_WQ, tile);
  } else {
    transpose_tile(Wv, WT + (size_t)(QSZ + KVSZ) * HIDN, KVSZ,
                   bid - NB_CONV - NB_WQ - NB_WK, tile);
  }
}

// ---- Wo [K=4096][N=2880] fp32 -> WT [2944 pad][4096] bf16 (fallback path) -
__global__ __launch_bounds__(256) void transpose_w(
    const float* __restrict__ W, unsigned short* __restrict__ WT,
    int K, int N)
{
  __shared__ float tile[32][72];
  const int tid = threadIdx.x;
  const int nb = blockIdx.x * 64;
  const int kb = blockIdx.y * 32;
  const int kk = tid >> 3;
  const int n8 = (tid & 7) * 8;
  if (nb + 64 <= N) {
    const float* src = W + (size_t)(kb + kk) * N + nb + n8;
    *(f32x4*)&tile[kk][n8]     = *(const f32x4*)(src);
    *(f32x4*)&tile[kk][n8 + 4] = *(const f32x4*)(src + 4);
  } else {
    #pragma unroll
    for (int u = 0; u < 8; ++u)
      tile[kk][n8 + u] = (nb + n8 + u < N)
          ? W[(size_t)(kb + kk) * N + nb + n8 + u] : 0.f;
  }
  __syncthreads();
  const int n  = tid & 63;
  const int k8 = (tid >> 6) * 8;
  bf16x8 p;
  #pragma unroll
  for (int j = 0; j < 8; ++j) p[j] = (short)f2bf(tile[k8 + j][n]);
  *(bf16x8*)(WT + (size_t)(nb + n) * K + kb + k8) = p;
}

// rope+bias epilogue for a 64-col group, 8 row-frags (per-wave 128 rows).
__device__ __forceinline__ void rope_epilogue8(
    f32x4 (*acc)[4], const float* __restrict__ bias,
    const int* __restrict__ pos, unsigned short* __restrict__ outp,
    int outStride, int colbase, int rowbase, int lane)
{
  const int fr = lane & 15;
  const int r4 = (lane >> 4) * 4;
  const float invf0 = exp2f((float)fr        * (-17.19460283f / 32.0f));
  const float invf1 = exp2f((float)(fr + 16) * (-17.19460283f / 32.0f));
  #pragma unroll
  for (int mt = 0; mt < 8; ++mt) {
    #pragma unroll
    for (int i = 0; i < 4; ++i) {
      const int m = rowbase + mt * 16 + r4 + i;
      const float p = (float)pos[m];
      #pragma unroll
      for (int ntp = 0; ntp < 2; ++ntp) {
        float sv, cv;
        __sincosf(p * (ntp ? invf1 : invf0), &sv, &cv);
        const int c1 = colbase + ntp * 16 + fr;
        const float x1 = acc[mt][ntp][i]     + bias[c1];
        const float x2 = acc[mt][ntp + 2][i] + bias[c1 + 32];
        outp[(size_t)m * outStride + c1]      = f2bf(x1 * cv - x2 * sv);
        outp[(size_t)m * outStride + c1 + 32] = f2bf(x1 * sv + x2 * cv);
      }
    }
  }
}

// ---- fused QKV GEMM: 256x256 tile, 8 waves, 8-phase counted-vmcnt pipeline
// (best-measured schedule: R6 bench 92.9-94.5 us). Stage schedule, tile t:
//   q0: A0(t+1) -> buf^1   q1: A1(t+1) -> buf^1
//   q2: B0(t+2) -> buf     q3: B1(t+2) -> buf   (B(t) dead after q0)
// vmcnt(4) at q3. XCD swizzle: n-chunked (B-panel L2-resident per XCD).
// blocks [0,160): GEMM.  blocks [160,256): Wo-transpose riders, each looping
// 31 tile-pairs with register prefetch (one rider per idle CU).
__global__ __launch_bounds__(512, 2) void gemm_qkv(
    const unsigned short* __restrict__ A, const unsigned short* __restrict__ BT,
    const float* __restrict__ bq, const float* __restrict__ bk,
    const float* __restrict__ bv, const int* __restrict__ pos,
    unsigned short* __restrict__ qb, unsigned short* __restrict__ kb,
    unsigned short* __restrict__ vT,
    const float* __restrict__ Wo, unsigned short* __restrict__ WoT)
{
  __shared__ unsigned short lds[65536];   // 128 KiB
  const int tid  = threadIdx.x;
  const int bid  = blockIdx.x;

  if (bid >= 160) {
    // ---- Wo transpose rider: 96 blocks x 2 halves x 31 tiles (64n x 32k) --
    const int half = tid >> 8;            // 0..1
    const int ltid = tid & 255;
    float* fb = (float*)lds;
    float (*tile)[72] = (float (*)[72])(fb + half * (32 * 72));
    const int slot = (bid - 160) * 2 + half;     // 0..191
    const int kk = ltid >> 3;
    const int n8 = (ltid & 7) * 8;
    const int n  = ltid & 63;
    const int k8 = (ltid >> 6) * 8;
    f32x4 va = {0.f, 0.f, 0.f, 0.f}, vb = {0.f, 0.f, 0.f, 0.f};
    int nb = 0, kb2 = 0;
    {
      const int t2 = slot * 31;
      if (t2 < 5888) {
        nb = (t2 % 46) * 64; kb2 = (t2 / 46) * 32;
        const float* src = Wo + (size_t)(kb2 + kk) * HIDN + nb + n8;
        if (nb + 64 <= HIDN) {
          va = *(const f32x4*)src; vb = *(const f32x4*)(src + 4);
        } else {
          #pragma unroll
          for (int u = 0; u < 4; ++u) {
            va[u] = (nb + n8 + u     < HIDN) ? src[u]     : 0.f;
            vb[u] = (nb + n8 + 4 + u < HIDN) ? src[4 + u] : 0.f;
          }
        }
      }
    }
    for (int it = 0; it < 31; ++it) {
      const int t2 = slot * 31 + it;
      const bool ok = t2 < 5888;
      const int cnb = nb, ckb = kb2;
      __syncthreads();                    // prior iter's transposed reads done
      if (ok) {
        *(f32x4*)&tile[kk][n8]     = va;
        *(f32x4*)&tile[kk][n8 + 4] = vb;
      }
      __syncthreads();
      const int t2n = t2 + 1;
      if (it + 1 < 31 && t2n < 5888) {    // prefetch next tile into regs
        nb = (t2n % 46) * 64; kb2 = (t2n / 46) * 32;
        const float* src = Wo + (size_t)(kb2 + kk) * HIDN + nb + n8;
        if (nb + 64 <= HIDN) {
          va = *(const f32x4*)src; vb = *(const f32x4*)(src + 4);
        } else {
          #pragma unroll
          for (int u = 0; u < 4; ++u) {
            va[u] = (nb + n8 + u     < HIDN) ? src[u]     : 0.f;
            vb[u] = (nb + n8 + 4 + u < HIDN) ? src[4 + u] : 0.f;
          }
        }
      }
      if (ok) {
        bf16x8 p;
        #pragma unroll
        for (int j = 0; j < 8; ++j) p[j] = (short)f2bf(tile[k8 + j][n]);
        *(bf16x8*)(WoT + (size_t)(cnb + n) * QSZ + ckb + k8) = p;
      }
    }
    return;
  }

  const int lane = tid & 63;
  const int wid  = tid >> 6;              // 0..7
  const int wm   = wid >> 2;              // 0..1  row half
  const int wn   = wid & 3;               // 0..3  64-col group
  const int wg   = (bid & 7) * 20 + (bid >> 3);
  const int n0   = (wg >> 3) * 256;       // n-chunked: B-panel L2-resident/XCD
  const int m0   = (wg & 7) * 256;
  const int fr = lane & 15;
  const int fq = lane >> 4;

  const int rsub = tid >> 3;                    // 0..63
  const int cg   = (tid & 7) ^ (rsub & 7);
  const unsigned short* Asrc = A  + (size_t)(m0 + rsub) * HIDN + cg * 8;
  const unsigned short* Bsrc = BT + (size_t)(n0 + rsub) * HIDN + cg * 8;
  const size_t half_step = (size_t)128 * HIDN;
  const size_t r64 = (size_t)64 * HIDN;

  #define STAGE(src, slot)                                         \
    do {                                                           \
      ld_g2l16((src),       (slot) + (size_t)tid * 8);             \
      ld_g2l16((src) + r64, (slot) + (size_t)(512 + tid) * 8);     \
    } while (0)

  STAGE(Bsrc,                  lds + 16384);
  STAGE(Bsrc + half_step,      lds + 24576);
  STAGE(Asrc,                  lds + 0);
  STAGE(Asrc + half_step,      lds + 8192);
  STAGE(Bsrc + 64,             lds + 32768 + 16384);
  STAGE(Bsrc + half_step + 64, lds + 32768 + 24576);
  STAGE(Asrc + 64,             lds + 32768 + 0);
  STAGE(Asrc + half_step + 64, lds + 32768 + 8192);
  asm volatile("s_waitcnt vmcnt(8)" ::: "memory");
  __builtin_amdgcn_s_barrier();

  f32x4 acc[8][4];
  #pragma unroll
  for (int i = 0; i < 8; ++i)
    #pragma unroll
    for (int j = 0; j < 4; ++j) acc[i][j] = (f32x4){0.f, 0.f, 0.f, 0.f};
  bf16x8 bfr[4][2];

  for (int t = 0; t < NT; ++t) {
    unsigned short* Abuf = lds + (t & 1) * 32768;
    unsigned short* Bbuf = Abuf + 16384;
    unsigned short* nAbuf = lds + ((t + 1) & 1) * 32768;
    const int kA = (t + 1) * 64;
    const int kB = (t + 2) * 64;
    #pragma unroll
    for (int q = 0; q < 4; ++q) {
      if (q == 0) {
        #pragma unroll
        for (int nf = 0; nf < 4; ++nf)
          #pragma unroll
          for (int ks = 0; ks < 2; ++ks) {
            const int R = wn * 64 + nf * 16 + fr;
            const int kc = ks * 4 + fq;
            bfr[nf][ks] = *(const bf16x8*)(Bbuf + R * 64 + ((kc ^ (R & 7)) << 3));
          }
      }
      bf16x8 af[2][2];
      #pragma unroll
      for (int j = 0; j < 2; ++j)
        #pragma unroll
        for (int ks = 0; ks < 2; ++ks) {
          const int R = wm * 128 + (q * 2 + j) * 16 + fr;
          const int kc = ks * 4 + fq;
          af[j][ks] = *(const bf16x8*)(Abuf + R * 64 + ((kc ^ (R & 7)) << 3));
        }
      if (q == 0) {
        if (t >= 1 && t <= NT - 2) STAGE(Asrc + kA, nAbuf);
      } else if (q == 1) {
        if (t >= 1 && t <= NT - 2) STAGE(Asrc + half_step + kA, nAbuf + 8192);
      } else if (q == 2) {
        if (t <= NT - 3) STAGE(Bsrc + kB, Bbuf);
      } else {
        if (t <= NT - 3) STAGE(Bsrc + half_step + kB, Bbuf + 8192);
      }
      if (q == 3) {
        if (t < NT - 2)       asm volatile("s_waitcnt vmcnt(4)" ::: "memory");
        else if (t == NT - 2) asm volatile("s_waitcnt vmcnt(0)" ::: "memory");
      }
      __builtin_amdgcn_s_barrier();
      __builtin_amdgcn_s_setprio(1);
      #pragma unroll
      for (int j = 0; j < 2; ++j)
        #pragma unroll
        for (int nf = 0; nf < 4; ++nf)
          #pragma unroll
          for (int ks = 0; ks < 2; ++ks)
            acc[q * 2 + j][nf] = __builtin_amdgcn_mfma_f32_16x16x32_bf16(
                af[j][ks], bfr[nf][ks], acc[q * 2 + j][nf], 0, 0, 0);
      __builtin_amdgcn_s_setprio(0);
      __builtin_amdgcn_s_barrier();
    }
  }
  #undef STAGE

  const int cb = n0 + wn * 64;
  const int rowbase = m0 + wm * 128;
  if (cb < QSZ) {
    rope_epilogue8(acc, bq, pos, qb, QSZ, cb, rowbase, lane);
  } else if (cb < QSZ + KVSZ) {
    rope_epilogue8(acc, bk, pos, kb, KVSZ, cb - QSZ, rowbase, lane);
  } else {
    const int r4 = (lane >> 4) * 4;
    #pragma unroll
    for (int nt = 0; nt < 4; ++nt) {
      const int vrow = cb - (QSZ + KVSZ) + nt * 16 + fr;
      const float bvv = bv[vrow];
      #pragma unroll
      for (int mt = 0; mt < 8; ++mt) {
        const int mb = rowbase + mt * 16 + r4;
        s16x4 p;
        p[0] = (short)f2bf(acc[mt][nt][0] + bvv);
        p[1] = (short)f2bf(acc[mt][nt][1] + bvv);
        p[2] = (short)f2bf(acc[mt][nt][2] + bvv);
        p[3] = (short)f2bf(acc[mt][nt][3] + bvv);
        *(s16x4*)(vT + (size_t)vrow * T_TOK + mb) = p;
      }
    }
  }
}

// ------- O-projection GEMM: 256m x 128n tile, 8 waves (4M x 2N),
// 2-phase-per-K-tile, TRIPLE-buffered A + double-buffered B, counted vmcnt.
// XCD swizzle: n-chunked (B=WoT chunk ~3 MB L2-resident per XCD; A streams).
__global__ __launch_bounds__(512, 2) void gemm_o(
    const unsigned short* __restrict__ A, const unsigned short* __restrict__ BT,
    const float* __restrict__ bias, float* __restrict__ C)
{
  __shared__ unsigned short lds[65536];   // 128 KiB
  const int tid  = threadIdx.x;
  const int lane = tid & 63;
  const int wid  = tid >> 6;
  const int wm   = wid >> 1;              // 0..3 row 64-group
  const int wn   = wid & 1;               // 0..1 col 64-group
  const int bid  = blockIdx.x;
  const int wg   = (bid & 7) * 23 + (bid >> 3);   // 184 = 8*23 bijective
  const int m0   = (wg & 7) * 256;        // n-chunked decode
  const int n0   = (wg >> 3) * 128;
  const int fr = lane & 15;
  const int fq = lane >> 4;

  const int rsub = tid >> 3;                    // 0..63
  const int cg   = (tid & 7) ^ (rsub & 7);
  const unsigned short* Asrc = A  + (size_t)(m0 + rsub) * QSZ + cg * 8;
  const unsigned short* Bsrc = BT + (size_t)(n0 + rsub) * QSZ + cg * 8;
  const size_t r64 = (size_t)64 * QSZ;

  #define STA(t, r)  ld_g2l16(Asrc + (size_t)(t) * 64 + (size_t)(r) * r64,   \
      lds + ((t) % 3) * 16384 + ((size_t)(r) * 512 + tid) * 8)
  #define STB(t, r)  ld_g2l16(Bsrc + (size_t)(t) * 64 + (size_t)(r) * r64,   \
      lds + 49152 + ((t) & 1) * 8192 + ((size_t)(r) * 512 + tid) * 8)

  STA(0, 0); STA(0, 1); STA(0, 2); STA(0, 3);
  STB(0, 0); STB(0, 1);
  STA(1, 0); STA(1, 1); STA(1, 2); STA(1, 3);
  STB(1, 0); STB(1, 1);
  asm volatile("s_waitcnt vmcnt(6)" ::: "memory");
  __builtin_amdgcn_s_barrier();

  f32x4 acc[4][4];
  #pragma unroll
  for (int i = 0; i < 4; ++i)
    #pragma unroll
    for (int j = 0; j < 4; ++j) acc[i][j] = (f32x4){0.f, 0.f, 0.f, 0.f};
  bf16x8 bfr[4][2];

  for (int t = 0; t < NTO; ++t) {
    unsigned short* Abuf = lds + (t % 3) * 16384;
    unsigned short* Bbuf = lds + 49152 + (t & 1) * 8192;
    #pragma unroll
    for (int nf = 0; nf < 4; ++nf)
      #pragma unroll
      for (int ks = 0; ks < 2; ++ks) {
        const int R = wn * 64 + nf * 16 + fr;
        const int kc = ks * 4 + fq;
        bfr[nf][ks] = *(const bf16x8*)(Bbuf + R * 64 + ((kc ^ (R & 7)) << 3));
      }
    bf16x8 af0[2][2];
    #pragma unroll
    for (int j = 0; j < 2; ++j)
      #pragma unroll
      for (int ks = 0; ks < 2; ++ks) {
        const int R = wm * 64 + j * 16 + fr;
        const int kc = ks * 4 + fq;
        af0[j][ks] = *(const bf16x8*)(Abuf + R * 64 + ((kc ^ (R & 7)) << 3));
      }
    if (t <= NTO - 3) { STA(t + 2, 0); STA(t + 2, 1); STA(t + 2, 2); STA(t + 2, 3); }
    __builtin_amdgcn_s_barrier();
    __builtin_amdgcn_s_setprio(1);
    #pragma unroll
    for (int j = 0; j < 2; ++j)
      #pragma unroll
      for (int nf = 0; nf < 4; ++nf)
        #pragma unroll
        for (int ks = 0; ks < 2; ++ks)
          acc[j][nf] = __builtin_amdgcn_mfma_f32_16x16x32_bf16(
              af0[j][ks], bfr[nf][ks], acc[j][nf], 0, 0, 0);
    __builtin_amdgcn_s_setprio(0);
    __builtin_amdgcn_s_barrier();
    bf16x8 af1[2][2];
    #pragma unroll
    for (int j = 0; j < 2; ++j)
      #pragma unroll
      for (int ks = 0; ks < 2; ++ks) {
        const int R = wm * 64 + (2 + j) * 16 + fr;
        const int kc = ks * 4 + fq;
        af1[j][ks] = *(const bf16x8*)(Abuf + R * 64 + ((kc ^ (R & 7)) << 3));
      }
    if (t <= NTO - 3) { STB(t + 2, 0); STB(t + 2, 1); }
    if (t <= NTO - 3)      asm volatile("s_waitcnt vmcnt(6)" ::: "memory");
    else if (t == NTO - 2) asm volatile("s_waitcnt vmcnt(0)" ::: "memory");
    __builtin_amdgcn_s_barrier();
    __builtin_amdgcn_s_setprio(1);
    #pragma unroll
    for (int j = 0; j < 2; ++j)
      #pragma unroll
      for (int nf = 0; nf < 4; ++nf)
        #pragma unroll
        for (int ks = 0; ks < 2; ++ks)
          acc[2 + j][nf] = __builtin_amdgcn_mfma_f32_16x16x32_bf16(
              af1[j][ks], bfr[nf][ks], acc[2 + j][nf], 0, 0, 0);
    __builtin_amdgcn_s_setprio(0);
    __builtin_amdgcn_s_barrier();
  }
  #undef STA
  #undef STB

  const int r4 = (lane >> 4) * 4;
  #pragma unroll
  for (int nt = 0; nt < 4; ++nt) {
    const int n = n0 + wn * 64 + nt * 16 + fr;
    if (n >= HIDN) continue;
    const float bvv = bias[n];
    #pragma unroll
    for (int mt = 0; mt < 4; ++mt) {
      const int mb = m0 + wm * 64 + mt * 16 + r4;
      #pragma unroll
      for (int i = 0; i < 4; ++i)
        C[(size_t)(mb + i) * HIDN + n] = acc[mt][nt][i] + bvv;
    }
  }
}

// ---------------- MFMA sliding-window GQA attention, 2 heads/block --------
// Per-wave windowing: wave w owns q-rows [sq0+16w, sq0+16w+15]; its valid key
// range is exactly tiles [w, w+8] (144 keys) of the 192-key staging window.
__global__ __launch_bounds__(256, 3) void attn_kernel(
    const unsigned short* __restrict__ q, const unsigned short* __restrict__ k,
    const unsigned short* __restrict__ vT, unsigned short* __restrict__ o)
{
  __shared__ unsigned short lds[26624];     // 53,248 B -> 3 blocks/CU
  unsigned short* Ks = lds;                 // [192][72]
  unsigned short* Vt = lds;                 // [64][200] (over Ks)
  unsigned short* Ps = lds + 13824;         // [64][200]

  const int tid  = threadIdx.x;
  const int lane = tid & 63;
  const int wid  = tid >> 6;
  const int sq0  = blockIdx.x * 64;
  const int hp   = blockIdx.y;
  const int b    = blockIdx.z;
  const int h0   = hp * 2;
  const int kvh  = hp >> 2;
  const int kp0  = sq0 - WIN;

  const int fr = lane & 15;
  const int fk = (lane >> 4) * 8;
  const int qw = wid * 16;
  const int ntb = wid;                      // wave's first valid K-tile

  bf16x8 qf[2][2];
  {
    const size_t qrow = (size_t)(b * S_LEN + sq0 + qw + fr) * QSZ;
    #pragma unroll
    for (int hh = 0; hh < 2; ++hh)
      #pragma unroll
      for (int ks2 = 0; ks2 < 2; ++ks2)
        qf[hh][ks2] = *(const bf16x8*)(q + qrow + (h0 + hh) * DH + ks2 * 32 + fk);
  }

  #pragma unroll
  for (int j = 0; j < 6; ++j) {
    const int c  = tid + j * 256;
    const int kr = c >> 3, dc = (c & 7) * 8;
    int tok = b * S_LEN + kp0 + kr;
    if (tok < 0) tok = 0;                   // masked later
    const bf16x8 vv = *(const bf16x8*)(k + (size_t)tok * KVSZ + kvh * DH + dc);
    *(bf16x8*)&Ks[kr * 72 + dc] = vv;
  }
  __syncthreads();

  f32x4 S0[9], S1[9];
  #pragma unroll
  for (int i = 0; i < 9; ++i) {
    S0[i] = (f32x4){0.f, 0.f, 0.f, 0.f};
    S1[i] = (f32x4){0.f, 0.f, 0.f, 0.f};
  }
  #pragma unroll
  for (int ks2 = 0; ks2 < 2; ++ks2) {
    #pragma unroll
    for (int j = 0; j < 9; ++j) {
      const bf16x8 bfr =
          *(const bf16x8*)&Ks[((ntb + j) * 16 + fr) * 72 + ks2 * 32 + fk];
      S0[j] = __builtin_amdgcn_mfma_f32_16x16x32_bf16(qf[0][ks2], bfr, S0[j], 0, 0, 0);
      S1[j] = __builtin_amdgcn_mfma_f32_16x16x32_bf16(qf[1][ks2], bfr, S1[j], 0, 0, 0);
    }
  }

  const int qbase = sq0 + qw + ((lane >> 4) << 2);
  float ls0[4] = {0.f, 0.f, 0.f, 0.f};
  float ls1[4] = {0.f, 0.f, 0.f, 0.f};
  #pragma unroll
  for (int j = 0; j < 9; ++j) {
    const int jpos = kp0 + (ntb + j) * 16 + fr;
    #pragma unroll
    for (int i = 0; i < 4; ++i) {
      const int qa = qbase + i;
      const bool valid = (jpos >= 0) && (jpos <= qa) && (jpos >= qa - WIN);
      const float e0 = valid ? __expf(S0[j][i] * 0.125f) : 0.f;
      const float e1 = valid ? __expf(S1[j][i] * 0.125f) : 0.f;
      S0[j][i] = e0; ls0[i] += e0;
      S1[j][i] = e1; ls1[i] += e1;
    }
  }
  #pragma unroll
  for (int off = 1; off < 16; off <<= 1)
    #pragma unroll
    for (int i = 0; i < 4; ++i) {
      ls0[i] += __shfl_xor(ls0[i], off, 64);
      ls1[i] += __shfl_xor(ls1[i], off, 64);
    }
  float inv0[4], inv1[4];
  #pragma unroll
  for (int i = 0; i < 4; ++i) {
    inv0[i] = 1.0f / ls0[i];
    inv1[i] = 1.0f / ls1[i];
  }
  __syncthreads();   // all waves done reading Ks

  #pragma unroll
  for (int j = 0; j < 9; ++j)
    #pragma unroll
    for (int i = 0; i < 4; ++i)
      Ps[(qbase - sq0 + i) * 200 + (ntb + j) * 16 + fr] = f2bf(S0[j][i]);
  {
    const int zt = (wid & 1) ? (wid - 1) : (wid + 9);   // zero-fill tile
    #pragma unroll
    for (int i = 0; i < 4; ++i)
      Ps[(qbase - sq0 + i) * 200 + zt * 16 + fr] = 0;
  }
  if (kp0 >= 0) {
    #pragma unroll
    for (int j = 0; j < 6; ++j) {
      const int c  = tid + j * 256;
      const int dr = c / 24, kc = (c % 24) * 8;
      const bf16x8 vv = *(const bf16x8*)(
          vT + (size_t)(kvh * DH + dr) * T_TOK + b * S_LEN + kp0 + kc);
      *(bf16x8*)&Vt[dr * 200 + kc] = vv;
    }
  } else {
    #pragma unroll
    for (int j = 0; j < 6; ++j) {
      const int c  = tid + j * 256;
      const int dr = c / 24, kc = (c % 24) * 8;
      bf16x8 vv;
      #pragma unroll
      for (int u = 0; u < 8; ++u) {
        int col = b * S_LEN + kp0 + kc + u;
        if (col < 0) col = 0;               // p==0 there
        vv[u] = (short)vT[(size_t)(kvh * DH + dr) * T_TOK + col];
      }
      *(bf16x8*)&Vt[dr * 200 + kc] = vv;
    }
  }
  __syncthreads();

  const int ks0 = wid >> 1;                 // wave's first PV 32-col block
  {
    f32x4 O[4];
    #pragma unroll
    for (int i = 0; i < 4; ++i) O[i] = (f32x4){0.f, 0.f, 0.f, 0.f};
    #pragma unroll
    for (int kq = 0; kq < 5; ++kq) {
      const int ks2 = ks0 + kq;
      const bf16x8 pa = *(const bf16x8*)&Ps[(qw + fr) * 200 + ks2 * 32 + fk];
      #pragma unroll
      for (int nt = 0; nt < 4; ++nt) {
        const bf16x8 vb = *(const bf16x8*)&Vt[(nt * 16 + fr) * 200 + ks2 * 32 + fk];
        O[nt] = __builtin_amdgcn_mfma_f32_16x16x32_bf16(pa, vb, O[nt], 0, 0, 0);
      }
    }
    #pragma unroll
    for (int nt = 0; nt < 4; ++nt)
      #pragma unroll
      for (int i = 0; i < 4; ++i)
        o[(size_t)(b * S_LEN + qbase + i) * QSZ + h0 * DH + nt * 16 + fr] =
            f2bf(O[nt][i] * inv0[i]);
  }
  __syncthreads();   // all waves done reading P0

  #pragma unroll
  for (int j = 0; j < 9; ++j)
    #pragma unroll
    for (int i = 0; i < 4; ++i)
      Ps[(qbase - sq0 + i) * 200 + (ntb + j) * 16 + fr] = f2bf(S1[j][i]);
  __syncthreads();

  {
    f32x4 O[4];
    #pragma unroll
    for (int i = 0; i < 4; ++i) O[i] = (f32x4){0.f, 0.f, 0.f, 0.f};
    #pragma unroll
    for (int kq = 0; kq < 5; ++kq) {
      const int ks2 = ks0 + kq;
      const bf16x8 pa = *(const bf16x8*)&Ps[(qw + fr) * 200 + ks2 * 32 + fk];
      #pragma unroll
      for (int nt = 0; nt < 4; ++nt) {
        const bf16x8 vb = *(const bf16x8*)&Vt[(nt * 16 + fr) * 200 + ks2 * 32 + fk];
        O[nt] = __builtin_amdgcn_mfma_f32_16x16x32_bf16(pa, vb, O[nt], 0, 0, 0);
      }
    }
    #pragma unroll
    for (int nt = 0; nt < 4; ++nt)
      #pragma unroll
      for (int i = 0; i < 4; ++i)
        o[(size_t)(b * S_LEN + qbase + i) * QSZ + (h0 + 1) * DH + nt * 16 + fr] =
            f2bf(O[nt][i] * inv1[i]);
  }
}

extern "C" void kernel_launch(void* const* d_in, const int* in_sizes, int n_in,
                              void* d_out, int out_size, void* d_ws, size_t ws_size,
                              hipStream_t stream) {
  const float* hidden    = (const float*)d_in[0];
  const int*   positions = (const int*)d_in[1];
  const float* Wq = (const float*)d_in[2];
  const float* bq = (const float*)d_in[3];
  const float* Wk = (const float*)d_in[4];
  const float* bk = (const float*)d_in[5];
  const float* Wv = (const float*)d_in[6];
  const float* bv = (const float*)d_in[7];
  const float* Wo = (const float*)d_in[8];
  const float* bo = (const float*)d_in[9];
  float* out = (float*)d_out;

  // workspace:
  //   hbf   [2048][2880] bf16        @ 0          (11,796,480)
  //   WqkvT [5120][2880] bf16        @ 11796480
  //   q/o   [2048][4096] bf16        @ 41287680
  //   k     [2048][512]  bf16        @ 58064896
  //   vT    [512][2048]  bf16        @ 60162048   (ends 62,259,200)
  //   WoT   [2944][4096] bf16        @ 62259200   (needs ws >= 86,376,448)
  char* ws = (char*)d_ws;
  unsigned short* hbf   = (unsigned short*)(ws);
  unsigned short* WqkvT = (unsigned short*)(ws + 11796480);
  unsigned short* qb    = (unsigned short*)(ws + 41287680);
  unsigned short* kb    = (unsigned short*)(ws + 58064896);
  unsigned short* vTb   = (unsigned short*)(ws + 60162048);

  const bool merged = ws_size >= (size_t)86376448;
  unsigned short* WoT = merged ? (unsigned short*)(ws + 62259200) : WqkvT;

  prep_kernel<<<dim3(NB_CONV + NB_WQ + 2 * NB_WK), dim3(256), 0, stream>>>(
      hidden, hbf, Wq, Wk, Wv, WqkvT);

  if (merged) {
    // 96 looping Wo-transpose riders fill the CUs the 160 GEMM blocks leave idle
    gemm_qkv<<<dim3(256), dim3(512), 0, stream>>>(
        hbf, WqkvT, bq, bk, bv, positions, qb, kb, vTb, Wo, WoT);
  } else {
    gemm_qkv<<<dim3(160), dim3(512), 0, stream>>>(
        hbf, WqkvT, bq, bk, bv, positions, qb, kb, vTb, Wo, WoT);
    transpose_w<<<dim3(NOPAD / 64, QSZ / 32), dim3(256), 0, stream>>>(
        Wo, WqkvT, QSZ, HIDN);
  }

  attn_kernel<<<dim3(S_LEN / 64, NHQ / 2, 2), dim3(256), 0, stream>>>(
      qb, kb, vTb, qb);
  gemm_o<<<dim3(184), dim3(512), 0, stream>>>(
      qb, WoT, bo, out);
}